// Round 1
// baseline (2239.937 us; speedup 1.0000x reference)
//
#include <hip/hip_runtime.h>

#define TPB 256

__global__ void k_zero(int* __restrict__ p, int n) {
    int i = blockIdx.x * blockDim.x + threadIdx.x;
    if (i < n) p[i] = 0;
}

__global__ void k_deg(const int* __restrict__ dst, int* __restrict__ deg, int E) {
    int i = blockIdx.x * blockDim.x + threadIdx.x;
    if (i < E) atomicAdd(&deg[dst[i]], 1);
}

__global__ void k_dis(const int* __restrict__ deg, float* __restrict__ dis, int N) {
    int v = blockIdx.x * blockDim.x + threadIdx.x;
    if (v < N) dis[v] = rsqrtf((float)(deg[v] + 1));  // +1 self-loop
}

// hs1[v] = (x[v] @ W1) * dis[v];  agg1[v] = hs1[v]  (self-loop contribution)
__global__ void k_lin1(const float* __restrict__ x, const float* __restrict__ W1,
                       const float* __restrict__ dis, float* __restrict__ hs1,
                       float* __restrict__ agg1, int N) {
    __shared__ float w[64];
    if (threadIdx.x < 64) w[threadIdx.x] = W1[threadIdx.x];
    __syncthreads();
    int v = blockIdx.x * blockDim.x + threadIdx.x;
    if (v >= N) return;
    float4 xv = ((const float4*)x)[v];
    float d = dis[v];
#pragma unroll
    for (int j = 0; j < 16; j++) {
        float h = xv.x * w[j] + xv.y * w[16 + j] + xv.z * w[32 + j] + xv.w * w[48 + j];
        h *= d;
        hs1[v * 16 + j] = h;
        agg1[v * 16 + j] = h;
    }
}

// 4 threads per edge; each gathers a float4 of hs1[src] and atomically adds into agg1[dst]
__global__ void k_scat1(const int* __restrict__ src, const int* __restrict__ dst,
                        const float* __restrict__ hs1, float* __restrict__ agg1, int E4) {
    int t = blockIdx.x * blockDim.x + threadIdx.x;
    if (t >= E4) return;
    int e = t >> 2, q = t & 3;
    int s = src[e], d = dst[e];
    float4 m = ((const float4*)hs1)[s * 4 + q];
    float* a = agg1 + (size_t)d * 16 + q * 4;
    atomicAdd(a + 0, m.x);
    atomicAdd(a + 1, m.y);
    atomicAdd(a + 2, m.z);
    atomicAdd(a + 3, m.w);
}

// epilogue1 (bias + relu) fused with layer-2 linear + dis scale
__global__ void k_lin2(const float* __restrict__ agg1, const float* __restrict__ dis,
                       const float* __restrict__ b1, const float* __restrict__ W2,
                       float* __restrict__ hs2, float* __restrict__ agg2, int N) {
    __shared__ float w[32];
    __shared__ float bb[16];
    if (threadIdx.x < 32) w[threadIdx.x] = W2[threadIdx.x];
    if (threadIdx.x < 16) bb[threadIdx.x] = b1[threadIdx.x];
    __syncthreads();
    int v = blockIdx.x * blockDim.x + threadIdx.x;
    if (v >= N) return;
    float d = dis[v];
    float acc0 = 0.f, acc1 = 0.f;
#pragma unroll
    for (int k = 0; k < 16; k++) {
        float r = agg1[v * 16 + k] * d + bb[k];
        r = fmaxf(r, 0.0f);
        acc0 += r * w[k * 2 + 0];
        acc1 += r * w[k * 2 + 1];
    }
    float2 hv = make_float2(acc0 * d, acc1 * d);
    ((float2*)hs2)[v] = hv;
    ((float2*)agg2)[v] = hv;  // self-loop
}

__global__ void k_scat2(const int* __restrict__ src, const int* __restrict__ dst,
                        const float* __restrict__ hs2, float* __restrict__ agg2, int E) {
    int e = blockIdx.x * blockDim.x + threadIdx.x;
    if (e >= E) return;
    int s = src[e], d = dst[e];
    float2 m = ((const float2*)hs2)[s];
    atomicAdd(&agg2[d * 2 + 0], m.x);
    atomicAdd(&agg2[d * 2 + 1], m.y);
}

__global__ void k_out(const float* __restrict__ agg2, const float* __restrict__ dis,
                      const float* __restrict__ b2, float* __restrict__ out, int N) {
    int v = blockIdx.x * blockDim.x + threadIdx.x;
    if (v >= N) return;
    float d = dis[v];
    out[v * 2 + 0] = agg2[v * 2 + 0] * d + b2[0];
    out[v * 2 + 1] = agg2[v * 2 + 1] * d + b2[1];
}

extern "C" void kernel_launch(void* const* d_in, const int* in_sizes, int n_in,
                              void* d_out, int out_size, void* d_ws, size_t ws_size,
                              hipStream_t stream) {
    const float* x  = (const float*)d_in[0];
    const int*   ei = (const int*)d_in[1];
    const float* W1 = (const float*)d_in[2];
    const float* b1 = (const float*)d_in[3];
    const float* W2 = (const float*)d_in[4];
    const float* b2 = (const float*)d_in[5];

    const int N = in_sizes[0] / 4;   // 100000
    const int E = in_sizes[1] / 2;   // 6400000
    const int* src = ei;
    const int* dst = ei + E;

    // workspace layout (256B-aligned segments)
    auto align = [](size_t v) { return (v + 255) & ~(size_t)255; };
    char* ws = (char*)d_ws;
    int*   deg  = (int*)ws;   ws += align((size_t)N * sizeof(int));
    float* dis  = (float*)ws; ws += align((size_t)N * sizeof(float));
    float* hs1  = (float*)ws; ws += align((size_t)N * 16 * sizeof(float));
    float* agg1 = (float*)ws; ws += align((size_t)N * 16 * sizeof(float));
    float* hs2  = (float*)ws; ws += align((size_t)N * 2 * sizeof(float));
    float* agg2 = (float*)ws; ws += align((size_t)N * 2 * sizeof(float));
    float* outp = (float*)d_out;

    int gN = (N + TPB - 1) / TPB;
    int gE = (E + TPB - 1) / TPB;
    int gE4 = (E * 4 + TPB - 1) / TPB;

    k_zero<<<gN, TPB, 0, stream>>>(deg, N);
    k_deg<<<gE, TPB, 0, stream>>>(dst, deg, E);
    k_dis<<<gN, TPB, 0, stream>>>(deg, dis, N);
    k_lin1<<<gN, TPB, 0, stream>>>(x, W1, dis, hs1, agg1, N);
    k_scat1<<<gE4, TPB, 0, stream>>>(src, dst, hs1, agg1, E * 4);
    k_lin2<<<gN, TPB, 0, stream>>>(agg1, dis, b1, W2, hs2, agg2, N);
    k_scat2<<<gE, TPB, 0, stream>>>(src, dst, hs2, agg2, E);
    k_out<<<gN, TPB, 0, stream>>>(agg2, dis, b2, outp, N);
}

// Round 2
// 1064.272 us; speedup vs baseline: 2.1047x; 2.1047x over previous
//
#include <hip/hip_runtime.h>

#define TPB 256

// ---------------- common small kernels ----------------

__global__ void k_zero(int* __restrict__ p, int n) {
    int i = blockIdx.x * blockDim.x + threadIdx.x;
    if (i < n) p[i] = 0;
}

__global__ void k_deg(const int* __restrict__ dst, int* __restrict__ deg, int E) {
    int i = blockIdx.x * blockDim.x + threadIdx.x;
    if (i < E) atomicAdd(&deg[dst[i]], 1);
}

// hs1[v] = (x[v] @ W1) * dis[v]
__global__ void k_lin1(const float* __restrict__ x, const float* __restrict__ W1,
                       const float* __restrict__ dis, float* __restrict__ hs1, int N) {
    __shared__ float w[64];
    if (threadIdx.x < 64) w[threadIdx.x] = W1[threadIdx.x];
    __syncthreads();
    int v = blockIdx.x * blockDim.x + threadIdx.x;
    if (v >= N) return;
    float4 xv = ((const float4*)x)[v];
    float d = dis[v];
#pragma unroll
    for (int j = 0; j < 16; j++) {
        float h = xv.x * w[j] + xv.y * w[16 + j] + xv.z * w[32 + j] + xv.w * w[48 + j];
        hs1[v * 16 + j] = h * d;
    }
}

// ---------------- CSR build (counting sort by dst) ----------------

__global__ void k_scan1(const int* __restrict__ deg, int* __restrict__ offsets,
                        int* __restrict__ bsum, int N) {
    __shared__ int s[TPB];
    int i = blockIdx.x * TPB + threadIdx.x;
    int d = (i < N) ? deg[i] : 0;
    s[threadIdx.x] = d;
    __syncthreads();
    for (int off = 1; off < TPB; off <<= 1) {
        int t = (threadIdx.x >= off) ? s[threadIdx.x - off] : 0;
        __syncthreads();
        s[threadIdx.x] += t;
        __syncthreads();
    }
    if (i < N) offsets[i] = s[threadIdx.x] - d;  // exclusive within block
    if (threadIdx.x == TPB - 1) bsum[blockIdx.x] = s[TPB - 1];
}

__global__ void k_scan2(int* __restrict__ bsum, int nb) {
    __shared__ int s[512];
    int t = threadIdx.x;
    int d = (t < nb) ? bsum[t] : 0;
    s[t] = d;
    __syncthreads();
    for (int off = 1; off < 512; off <<= 1) {
        int v = (t >= off) ? s[t - off] : 0;
        __syncthreads();
        s[t] += v;
        __syncthreads();
    }
    if (t < nb) bsum[t] = s[t] - d;  // exclusive
}

// offsets += scanned block sums; init cursor; compute dis
__global__ void k_scan3(int* __restrict__ offsets, const int* __restrict__ bsum,
                        int* __restrict__ cursor, const int* __restrict__ deg,
                        float* __restrict__ dis, int N) {
    int i = blockIdx.x * TPB + threadIdx.x;
    if (i >= N) return;
    int o = offsets[i] + bsum[blockIdx.x];
    offsets[i] = o;
    cursor[i] = o;
    dis[i] = rsqrtf((float)(deg[i] + 1));  // +1 self-loop
}

__global__ void k_fill(const int* __restrict__ src, const int* __restrict__ dst,
                       int* __restrict__ cursor, int* __restrict__ sorted_src, int E) {
    int e = blockIdx.x * blockDim.x + threadIdx.x;
    if (e >= E) return;
    int pos = atomicAdd(&cursor[dst[e]], 1);
    sorted_src[pos] = src[e];
}

// ---------------- wave-per-node aggregation (no fp32 atomics) ----------------

// Layer-1 aggregate + fused layer-2 linear:
// agg_f = hs1_self[f] + sum_{e in CSR(v)} hs1[src_e][f]
// r_f = relu(agg_f * dis + b1[f]);  hs2[v] = (r . W2) * dis
__global__ void k_agg1(const int* __restrict__ sorted_src, const int* __restrict__ offsets,
                       const int* __restrict__ deg, const float* __restrict__ hs1,
                       const float* __restrict__ dis, const float* __restrict__ b1,
                       const float* __restrict__ W2, float* __restrict__ hs2, int N) {
    int wid = (blockIdx.x * blockDim.x + threadIdx.x) >> 6;  // node = wave id
    if (wid >= N) return;
    int lane = threadIdx.x & 63;
    int g = lane >> 4;       // edge subgroup 0..3
    int f = lane & 15;       // feature 0..15
    int start = offsets[wid];
    int end = start + deg[wid];
    float acc = 0.0f;
    for (int e = start + g; e < end; e += 4)
        acc += hs1[(size_t)sorted_src[e] * 16 + f];
    // reduce over the 4 edge subgroups (lanes with same f)
    acc += __shfl_xor(acc, 16, 64);
    acc += __shfl_xor(acc, 32, 64);
    float d = dis[wid];
    float r = (hs1[(size_t)wid * 16 + f] + acc) * d + b1[f];
    r = fmaxf(r, 0.0f);
    float s0 = r * W2[2 * f];
    float s1 = r * W2[2 * f + 1];
#pragma unroll
    for (int m = 1; m < 16; m <<= 1) {
        s0 += __shfl_xor(s0, m, 64);
        s1 += __shfl_xor(s1, m, 64);
    }
    if (lane == 0) ((float2*)hs2)[wid] = make_float2(s0 * d, s1 * d);
}

// Layer-2 aggregate + final bias -> out
__global__ void k_agg2(const int* __restrict__ sorted_src, const int* __restrict__ offsets,
                       const int* __restrict__ deg, const float* __restrict__ hs2,
                       const float* __restrict__ dis, const float* __restrict__ b2,
                       float* __restrict__ out, int N) {
    int wid = (blockIdx.x * blockDim.x + threadIdx.x) >> 6;
    if (wid >= N) return;
    int lane = threadIdx.x & 63;
    int g = lane >> 1;       // edge subgroup 0..31
    int f = lane & 1;        // feature 0..1
    int start = offsets[wid];
    int end = start + deg[wid];
    float acc = 0.0f;
    for (int e = start + g; e < end; e += 32)
        acc += hs2[(size_t)sorted_src[e] * 2 + f];
#pragma unroll
    for (int m = 2; m < 64; m <<= 1) acc += __shfl_xor(acc, m, 64);
    if (lane < 2) out[wid * 2 + f] = (hs2[(size_t)wid * 2 + f] + acc) * dis[wid] + b2[f];
}

// ---------------- fallback (atomic) kernels, used if ws too small ----------------

__global__ void k_lin1_fb(const float* __restrict__ x, const float* __restrict__ W1,
                          const float* __restrict__ dis, float* __restrict__ hs1,
                          float* __restrict__ agg1, int N) {
    __shared__ float w[64];
    if (threadIdx.x < 64) w[threadIdx.x] = W1[threadIdx.x];
    __syncthreads();
    int v = blockIdx.x * blockDim.x + threadIdx.x;
    if (v >= N) return;
    float4 xv = ((const float4*)x)[v];
    float d = dis[v];
#pragma unroll
    for (int j = 0; j < 16; j++) {
        float h = (xv.x * w[j] + xv.y * w[16 + j] + xv.z * w[32 + j] + xv.w * w[48 + j]) * d;
        hs1[v * 16 + j] = h;
        agg1[v * 16 + j] = h;
    }
}

__global__ void k_dis_fb(const int* __restrict__ deg, float* __restrict__ dis, int N) {
    int v = blockIdx.x * blockDim.x + threadIdx.x;
    if (v < N) dis[v] = rsqrtf((float)(deg[v] + 1));
}

__global__ void k_scat1_fb(const int* __restrict__ src, const int* __restrict__ dst,
                           const float* __restrict__ hs1, float* __restrict__ agg1, int E4) {
    int t = blockIdx.x * blockDim.x + threadIdx.x;
    if (t >= E4) return;
    int e = t >> 2, q = t & 3;
    int s = src[e], d = dst[e];
    float4 m = ((const float4*)hs1)[s * 4 + q];
    float* a = agg1 + (size_t)d * 16 + q * 4;
    atomicAdd(a + 0, m.x);
    atomicAdd(a + 1, m.y);
    atomicAdd(a + 2, m.z);
    atomicAdd(a + 3, m.w);
}

__global__ void k_lin2_fb(const float* __restrict__ agg1, const float* __restrict__ dis,
                          const float* __restrict__ b1, const float* __restrict__ W2,
                          float* __restrict__ hs2, float* __restrict__ agg2, int N) {
    __shared__ float w[32];
    __shared__ float bb[16];
    if (threadIdx.x < 32) w[threadIdx.x] = W2[threadIdx.x];
    if (threadIdx.x < 16) bb[threadIdx.x] = b1[threadIdx.x];
    __syncthreads();
    int v = blockIdx.x * blockDim.x + threadIdx.x;
    if (v >= N) return;
    float d = dis[v];
    float acc0 = 0.f, acc1 = 0.f;
#pragma unroll
    for (int k = 0; k < 16; k++) {
        float r = fmaxf(agg1[v * 16 + k] * d + bb[k], 0.0f);
        acc0 += r * w[k * 2 + 0];
        acc1 += r * w[k * 2 + 1];
    }
    float2 hv = make_float2(acc0 * d, acc1 * d);
    ((float2*)hs2)[v] = hv;
    ((float2*)agg2)[v] = hv;
}

__global__ void k_scat2_fb(const int* __restrict__ src, const int* __restrict__ dst,
                           const float* __restrict__ hs2, float* __restrict__ agg2, int E) {
    int e = blockIdx.x * blockDim.x + threadIdx.x;
    if (e >= E) return;
    int s = src[e], d = dst[e];
    float2 m = ((const float2*)hs2)[s];
    atomicAdd(&agg2[d * 2 + 0], m.x);
    atomicAdd(&agg2[d * 2 + 1], m.y);
}

__global__ void k_out_fb(const float* __restrict__ agg2, const float* __restrict__ dis,
                         const float* __restrict__ b2, float* __restrict__ out, int N) {
    int v = blockIdx.x * blockDim.x + threadIdx.x;
    if (v >= N) return;
    float d = dis[v];
    out[v * 2 + 0] = agg2[v * 2 + 0] * d + b2[0];
    out[v * 2 + 1] = agg2[v * 2 + 1] * d + b2[1];
}

// ---------------- launch ----------------

extern "C" void kernel_launch(void* const* d_in, const int* in_sizes, int n_in,
                              void* d_out, int out_size, void* d_ws, size_t ws_size,
                              hipStream_t stream) {
    const float* x  = (const float*)d_in[0];
    const int*   ei = (const int*)d_in[1];
    const float* W1 = (const float*)d_in[2];
    const float* b1 = (const float*)d_in[3];
    const float* W2 = (const float*)d_in[4];
    const float* b2 = (const float*)d_in[5];

    const int N = in_sizes[0] / 4;   // 100000
    const int E = in_sizes[1] / 2;   // 6400000
    const int* src = ei;
    const int* dst = ei + E;
    float* outp = (float*)d_out;

    auto align = [](size_t v) { return (v + 255) & ~(size_t)255; };
    const int gN = (N + TPB - 1) / TPB;
    const int gE = (E + TPB - 1) / TPB;
    const int nb = gN;  // scan blocks (<=512 assumed; 391 for N=100k)

    size_t need = align((size_t)N * 4) * 4 /*deg,dis,offsets,cursor*/ + align(512 * 4)
                + align((size_t)N * 16 * 4) /*hs1*/ + align((size_t)N * 2 * 4) /*hs2*/
                + align((size_t)E * 4) /*sorted_src*/;

    if (ws_size >= need && nb <= 512) {
        char* ws = (char*)d_ws;
        int*   deg     = (int*)ws;   ws += align((size_t)N * 4);
        float* dis     = (float*)ws; ws += align((size_t)N * 4);
        int*   offsets = (int*)ws;   ws += align((size_t)N * 4);
        int*   cursor  = (int*)ws;   ws += align((size_t)N * 4);
        int*   bsum    = (int*)ws;   ws += align(512 * 4);
        float* hs1     = (float*)ws; ws += align((size_t)N * 16 * 4);
        float* hs2     = (float*)ws; ws += align((size_t)N * 2 * 4);
        int*   ssrc    = (int*)ws;   ws += align((size_t)E * 4);

        const int gW = ((size_t)N * 64 + TPB - 1) / TPB;  // wave-per-node grids

        k_zero<<<gN, TPB, 0, stream>>>(deg, N);
        k_deg<<<gE, TPB, 0, stream>>>(dst, deg, E);
        k_scan1<<<gN, TPB, 0, stream>>>(deg, offsets, bsum, N);
        k_scan2<<<1, 512, 0, stream>>>(bsum, nb);
        k_scan3<<<gN, TPB, 0, stream>>>(offsets, bsum, cursor, deg, dis, N);
        k_lin1<<<gN, TPB, 0, stream>>>(x, W1, dis, hs1, N);
        k_fill<<<gE, TPB, 0, stream>>>(src, dst, cursor, ssrc, E);
        k_agg1<<<gW, TPB, 0, stream>>>(ssrc, offsets, deg, hs1, dis, b1, W2, hs2, N);
        k_agg2<<<gW, TPB, 0, stream>>>(ssrc, offsets, deg, hs2, dis, b2, outp, N);
    } else {
        // fallback: atomic-scatter pipeline (R1)
        char* ws = (char*)d_ws;
        int*   deg  = (int*)ws;   ws += align((size_t)N * 4);
        float* dis  = (float*)ws; ws += align((size_t)N * 4);
        float* hs1  = (float*)ws; ws += align((size_t)N * 16 * 4);
        float* agg1 = (float*)ws; ws += align((size_t)N * 16 * 4);
        float* hs2  = (float*)ws; ws += align((size_t)N * 2 * 4);
        float* agg2 = (float*)ws; ws += align((size_t)N * 2 * 4);
        int gE4 = ((size_t)E * 4 + TPB - 1) / TPB;

        k_zero<<<gN, TPB, 0, stream>>>(deg, N);
        k_deg<<<gE, TPB, 0, stream>>>(dst, deg, E);
        k_dis_fb<<<gN, TPB, 0, stream>>>(deg, dis, N);
        k_lin1_fb<<<gN, TPB, 0, stream>>>(x, W1, dis, hs1, agg1, N);
        k_scat1_fb<<<gE4, TPB, 0, stream>>>(src, dst, hs1, agg1, E * 4);
        k_lin2_fb<<<gN, TPB, 0, stream>>>(agg1, dis, b1, W2, hs2, agg2, N);
        k_scat2_fb<<<gE, TPB, 0, stream>>>(src, dst, hs2, agg2, E);
        k_out_fb<<<gN, TPB, 0, stream>>>(agg2, dis, b2, outp, N);
    }
}

// Round 3
// 1013.676 us; speedup vs baseline: 2.2097x; 1.0499x over previous
//
#include <hip/hip_runtime.h>

#define TPB 256
#define BSH 7                 // nodes per bucket = 128
#define BNODES 128
#define EPW 8192              // edges per workgroup in passA

// ---------------- small utils ----------------

__global__ void k_zero(int* __restrict__ p, int n) {
    int i = blockIdx.x * blockDim.x + threadIdx.x;
    if (i < n) p[i] = 0;
}

// ---------------- bucket histogram (LDS-aggregated) ----------------

__global__ void k_hist(const int* __restrict__ dst, int* __restrict__ bcnt, int E, int NB) {
    extern __shared__ int cnt[];
    for (int i = threadIdx.x; i < NB; i += TPB) cnt[i] = 0;
    __syncthreads();
    int per = (E + gridDim.x - 1) / gridDim.x;
    int s = blockIdx.x * per;
    int e = min(E, s + per);
    for (int i = s + threadIdx.x; i < e; i += TPB)
        atomicAdd(&cnt[dst[i] >> BSH], 1);
    __syncthreads();
    for (int i = threadIdx.x; i < NB; i += TPB)
        if (cnt[i]) atomicAdd(&bcnt[i], cnt[i]);
}

// ---------------- exclusive scan of bucket counts (1 wg) ----------------

__global__ void k_scanb(const int* __restrict__ bcnt, int* __restrict__ bbase,
                        int* __restrict__ cursor, int NB) {
    __shared__ int sh[TPB];
    __shared__ int carry;
    if (threadIdx.x == 0) carry = 0;
    __syncthreads();
    for (int c0 = 0; c0 < NB; c0 += TPB) {
        int i = c0 + threadIdx.x;
        int v = (i < NB) ? bcnt[i] : 0;
        sh[threadIdx.x] = v;
        __syncthreads();
        for (int off = 1; off < TPB; off <<= 1) {
            int t = (threadIdx.x >= off) ? sh[threadIdx.x - off] : 0;
            __syncthreads();
            sh[threadIdx.x] += t;
            __syncthreads();
        }
        int total = sh[TPB - 1];
        int ex = carry + sh[threadIdx.x] - v;
        __syncthreads();
        if (threadIdx.x == 0) carry += total;
        __syncthreads();
        if (i < NB) { bbase[i] = ex; cursor[i] = ex; }
    }
    if (threadIdx.x == 0) bbase[NB] = carry;  // == E
}

// ---------------- pass A: partition edges into buckets, packed (src<<7|dstLocal) ----------------

__global__ void k_passA(const int* __restrict__ src, const int* __restrict__ dst,
                        int* __restrict__ cursor, unsigned* __restrict__ packed,
                        int E, int NB) {
    extern __shared__ int sh[];
    int* cnt = sh;          // [NB]
    int* wbase = sh + NB;   // [NB]
    for (int i = threadIdx.x; i < NB; i += TPB) cnt[i] = 0;
    __syncthreads();
    int base = blockIdx.x * EPW;
    int eend = min(E, base + EPW);
    for (int i = base + threadIdx.x; i < eend; i += TPB)
        atomicAdd(&cnt[dst[i] >> BSH], 1);
    __syncthreads();
    for (int b = threadIdx.x; b < NB; b += TPB) {
        int c = cnt[b];
        if (c) wbase[b] = atomicAdd(&cursor[b], c);
        cnt[b] = 0;
    }
    __syncthreads();
    for (int i = base + threadIdx.x; i < eend; i += TPB) {
        int d = dst[i];
        int b = d >> BSH;
        int r = atomicAdd(&cnt[b], 1);
        packed[wbase[b] + r] = ((unsigned)src[i] << BSH) | (unsigned)(d & (BNODES - 1));
    }
}

// ---------------- per-bucket: degree->dis, then hs1 = (x@W1)*dis ----------------

__global__ void k_prep(const unsigned* __restrict__ packed, const int* __restrict__ bbase,
                       const float* __restrict__ x, const float* __restrict__ W1,
                       float* __restrict__ dis, float* __restrict__ hs1, int N) {
    __shared__ int cnt[BNODES];
    __shared__ float w[64];
    __shared__ float disl[BNODES];
    int b = blockIdx.x;
    int node0 = b << BSH;
    if (threadIdx.x < BNODES) cnt[threadIdx.x] = 0;
    if (threadIdx.x < 64) w[threadIdx.x] = W1[threadIdx.x];
    __syncthreads();
    int e0 = bbase[b], e1 = bbase[b + 1];
    for (int i = e0 + threadIdx.x; i < e1; i += TPB)
        atomicAdd(&cnt[packed[i] & (BNODES - 1)], 1);
    __syncthreads();
    if (threadIdx.x < BNODES && node0 + threadIdx.x < N) {
        float di = rsqrtf((float)(cnt[threadIdx.x] + 1));  // +1 self-loop
        disl[threadIdx.x] = di;
        dis[node0 + threadIdx.x] = di;
    }
    __syncthreads();
    int v = threadIdx.x >> 1;
    int half = threadIdx.x & 1;
    if (v < BNODES && node0 + v < N) {
        float4 xv = ((const float4*)x)[node0 + v];
        float di = disl[v];
#pragma unroll
        for (int jj = 0; jj < 8; jj++) {
            int j = half * 8 + jj;
            float h = xv.x * w[j] + xv.y * w[16 + j] + xv.z * w[32 + j] + xv.w * w[48 + j];
            hs1[(size_t)(node0 + v) * 16 + j] = h * di;
        }
    }
}

// ---------------- layer-1 aggregate (LDS acc) + fused layer-2 linear ----------------

#define ASTRIDE 17  // pad to kill 32-way bank conflicts in epilogue

__global__ void k_agg1b(const unsigned* __restrict__ packed, const int* __restrict__ bbase,
                        const float* __restrict__ hs1, const float* __restrict__ dis,
                        const float* __restrict__ b1, const float* __restrict__ W2,
                        float* __restrict__ hs2, int N) {
    __shared__ float acc[BNODES * ASTRIDE];
    __shared__ float w2[32];
    __shared__ float bb[16];
    if (threadIdx.x < 32) w2[threadIdx.x] = W2[threadIdx.x];
    if (threadIdx.x < 16) bb[threadIdx.x] = b1[threadIdx.x];
    for (int i = threadIdx.x; i < BNODES * ASTRIDE; i += TPB) acc[i] = 0.0f;
    __syncthreads();
    int b = blockIdx.x;
    int node0 = b << BSH;
    int e0 = bbase[b], e1 = bbase[b + 1];
    int gg = threadIdx.x >> 4;   // 16 groups of 16 lanes
    int f = threadIdx.x & 15;
    for (int e = e0 + gg; e < e1; e += 16) {
        unsigned pk = packed[e];
        int s = pk >> BSH;
        int dl = pk & (BNODES - 1);
        atomicAdd(&acc[dl * ASTRIDE + f], hs1[(size_t)s * 16 + f]);
    }
    __syncthreads();
    int t = threadIdx.x;
    if (t < BNODES && node0 + t < N) {
        float di = dis[node0 + t];
        float s0 = 0.f, s1 = 0.f;
#pragma unroll
        for (int j = 0; j < 16; j++) {
            float r = (acc[t * ASTRIDE + j] + hs1[(size_t)(node0 + t) * 16 + j]) * di + bb[j];
            r = fmaxf(r, 0.0f);
            s0 += r * w2[2 * j];
            s1 += r * w2[2 * j + 1];
        }
        ((float2*)hs2)[node0 + t] = make_float2(s0 * di, s1 * di);
    }
}

// ---------------- layer-2 aggregate (LDS acc) + final bias -> out ----------------

__global__ void k_agg2b(const unsigned* __restrict__ packed, const int* __restrict__ bbase,
                        const float* __restrict__ hs2, const float* __restrict__ dis,
                        const float* __restrict__ b2, float* __restrict__ out, int N) {
    __shared__ float acc[BNODES * 2];
    for (int i = threadIdx.x; i < BNODES * 2; i += TPB) acc[i] = 0.0f;
    __syncthreads();
    int b = blockIdx.x;
    int node0 = b << BSH;
    int e0 = bbase[b], e1 = bbase[b + 1];
    int gg = threadIdx.x >> 1;   // 128 groups of 2 lanes
    int f = threadIdx.x & 1;
    for (int e = e0 + gg; e < e1; e += 128) {
        unsigned pk = packed[e];
        int s = pk >> BSH;
        int dl = pk & (BNODES - 1);
        atomicAdd(&acc[dl * 2 + f], hs2[(size_t)s * 2 + f]);
    }
    __syncthreads();
    int v = threadIdx.x >> 1;
    if (v < BNODES && node0 + v < N) {
        float r = (acc[v * 2 + f] + hs2[(size_t)(node0 + v) * 2 + f]) * dis[node0 + v] + b2[f];
        out[(size_t)(node0 + v) * 2 + f] = r;
    }
}

// ---------------- fallback (R1 atomic pipeline) ----------------

__global__ void k_deg_fb(const int* __restrict__ dst, int* __restrict__ deg, int E) {
    int i = blockIdx.x * blockDim.x + threadIdx.x;
    if (i < E) atomicAdd(&deg[dst[i]], 1);
}
__global__ void k_dis_fb(const int* __restrict__ deg, float* __restrict__ dis, int N) {
    int v = blockIdx.x * blockDim.x + threadIdx.x;
    if (v < N) dis[v] = rsqrtf((float)(deg[v] + 1));
}
__global__ void k_lin1_fb(const float* __restrict__ x, const float* __restrict__ W1,
                          const float* __restrict__ dis, float* __restrict__ hs1,
                          float* __restrict__ agg1, int N) {
    __shared__ float w[64];
    if (threadIdx.x < 64) w[threadIdx.x] = W1[threadIdx.x];
    __syncthreads();
    int v = blockIdx.x * blockDim.x + threadIdx.x;
    if (v >= N) return;
    float4 xv = ((const float4*)x)[v];
    float d = dis[v];
#pragma unroll
    for (int j = 0; j < 16; j++) {
        float h = (xv.x * w[j] + xv.y * w[16 + j] + xv.z * w[32 + j] + xv.w * w[48 + j]) * d;
        hs1[v * 16 + j] = h;
        agg1[v * 16 + j] = h;
    }
}
__global__ void k_scat1_fb(const int* __restrict__ src, const int* __restrict__ dst,
                           const float* __restrict__ hs1, float* __restrict__ agg1, int E4) {
    int t = blockIdx.x * blockDim.x + threadIdx.x;
    if (t >= E4) return;
    int e = t >> 2, q = t & 3;
    int s = src[e], d = dst[e];
    float4 m = ((const float4*)hs1)[s * 4 + q];
    float* a = agg1 + (size_t)d * 16 + q * 4;
    atomicAdd(a + 0, m.x); atomicAdd(a + 1, m.y);
    atomicAdd(a + 2, m.z); atomicAdd(a + 3, m.w);
}
__global__ void k_lin2_fb(const float* __restrict__ agg1, const float* __restrict__ dis,
                          const float* __restrict__ b1, const float* __restrict__ W2,
                          float* __restrict__ hs2, float* __restrict__ agg2, int N) {
    __shared__ float w[32];
    __shared__ float bb[16];
    if (threadIdx.x < 32) w[threadIdx.x] = W2[threadIdx.x];
    if (threadIdx.x < 16) bb[threadIdx.x] = b1[threadIdx.x];
    __syncthreads();
    int v = blockIdx.x * blockDim.x + threadIdx.x;
    if (v >= N) return;
    float d = dis[v];
    float a0 = 0.f, a1 = 0.f;
#pragma unroll
    for (int k = 0; k < 16; k++) {
        float r = fmaxf(agg1[v * 16 + k] * d + bb[k], 0.0f);
        a0 += r * w[k * 2 + 0];
        a1 += r * w[k * 2 + 1];
    }
    float2 hv = make_float2(a0 * d, a1 * d);
    ((float2*)hs2)[v] = hv;
    ((float2*)agg2)[v] = hv;
}
__global__ void k_scat2_fb(const int* __restrict__ src, const int* __restrict__ dst,
                           const float* __restrict__ hs2, float* __restrict__ agg2, int E) {
    int e = blockIdx.x * blockDim.x + threadIdx.x;
    if (e >= E) return;
    int s = src[e], d = dst[e];
    float2 m = ((const float2*)hs2)[s];
    atomicAdd(&agg2[d * 2 + 0], m.x);
    atomicAdd(&agg2[d * 2 + 1], m.y);
}
__global__ void k_out_fb(const float* __restrict__ agg2, const float* __restrict__ dis,
                         const float* __restrict__ b2, float* __restrict__ out, int N) {
    int v = blockIdx.x * blockDim.x + threadIdx.x;
    if (v >= N) return;
    float d = dis[v];
    out[v * 2 + 0] = agg2[v * 2 + 0] * d + b2[0];
    out[v * 2 + 1] = agg2[v * 2 + 1] * d + b2[1];
}

// ---------------- launch ----------------

extern "C" void kernel_launch(void* const* d_in, const int* in_sizes, int n_in,
                              void* d_out, int out_size, void* d_ws, size_t ws_size,
                              hipStream_t stream) {
    const float* x  = (const float*)d_in[0];
    const int*   ei = (const int*)d_in[1];
    const float* W1 = (const float*)d_in[2];
    const float* b1 = (const float*)d_in[3];
    const float* W2 = (const float*)d_in[4];
    const float* b2 = (const float*)d_in[5];

    const int N = in_sizes[0] / 4;   // 100000
    const int E = in_sizes[1] / 2;   // 6400000
    const int* src = ei;
    const int* dst = ei + E;
    float* outp = (float*)d_out;

    auto align = [](size_t v) { return (v + 255) & ~(size_t)255; };
    const int NB = (N + BNODES - 1) >> BSH;

    size_t need = align((size_t)E * 4)            /* packed */
                + align((size_t)N * 4)            /* dis */
                + align((size_t)N * 16 * 4)       /* hs1 */
                + align((size_t)N * 2 * 4)        /* hs2 */
                + align((size_t)NB * 4) * 2       /* bcnt, cursor */
                + align((size_t)(NB + 1) * 4);    /* bbase */

    if (ws_size >= need && (size_t)N <= (1u << 25) && NB <= 4096) {
        char* ws = (char*)d_ws;
        unsigned* packed = (unsigned*)ws; ws += align((size_t)E * 4);
        float* dis  = (float*)ws; ws += align((size_t)N * 4);
        float* hs1  = (float*)ws; ws += align((size_t)N * 16 * 4);
        float* hs2  = (float*)ws; ws += align((size_t)N * 2 * 4);
        int* bcnt   = (int*)ws;   ws += align((size_t)NB * 4);
        int* cursor = (int*)ws;   ws += align((size_t)NB * 4);
        int* bbase  = (int*)ws;   ws += align((size_t)(NB + 1) * 4);

        int gA = (E + EPW - 1) / EPW;

        k_zero<<<(NB + TPB - 1) / TPB, TPB, 0, stream>>>(bcnt, NB);
        k_hist<<<512, TPB, (size_t)NB * 4, stream>>>(dst, bcnt, E, NB);
        k_scanb<<<1, TPB, 0, stream>>>(bcnt, bbase, cursor, NB);
        k_passA<<<gA, TPB, (size_t)NB * 8, stream>>>(src, dst, cursor, packed, E, NB);
        k_prep<<<NB, TPB, 0, stream>>>(packed, bbase, x, W1, dis, hs1, N);
        k_agg1b<<<NB, TPB, 0, stream>>>(packed, bbase, hs1, dis, b1, W2, hs2, N);
        k_agg2b<<<NB, TPB, 0, stream>>>(packed, bbase, hs2, dis, b2, outp, N);
    } else {
        // fallback: R1 atomic-scatter pipeline
        char* ws = (char*)d_ws;
        int*   deg  = (int*)ws;   ws += align((size_t)N * 4);
        float* dis  = (float*)ws; ws += align((size_t)N * 4);
        float* hs1  = (float*)ws; ws += align((size_t)N * 16 * 4);
        float* agg1 = (float*)ws; ws += align((size_t)N * 16 * 4);
        float* hs2  = (float*)ws; ws += align((size_t)N * 2 * 4);
        float* agg2 = (float*)ws; ws += align((size_t)N * 2 * 4);
        int gN = (N + TPB - 1) / TPB;
        int gE = (E + TPB - 1) / TPB;
        int gE4 = ((size_t)E * 4 + TPB - 1) / TPB;

        k_zero<<<gN, TPB, 0, stream>>>(deg, N);
        k_deg_fb<<<gE, TPB, 0, stream>>>(dst, deg, E);
        k_dis_fb<<<gN, TPB, 0, stream>>>(deg, dis, N);
        k_lin1_fb<<<gN, TPB, 0, stream>>>(x, W1, dis, hs1, agg1, N);
        k_scat1_fb<<<gE4, TPB, 0, stream>>>(src, dst, hs1, agg1, E * 4);
        k_lin2_fb<<<gN, TPB, 0, stream>>>(agg1, dis, b1, W2, hs2, agg2, N);
        k_scat2_fb<<<gE, TPB, 0, stream>>>(src, dst, hs2, agg2, E);
        k_out_fb<<<gN, TPB, 0, stream>>>(agg2, dis, b2, outp, N);
    }
}

// Round 4
// 997.237 us; speedup vs baseline: 2.2461x; 1.0165x over previous
//
#include <hip/hip_runtime.h>

#define TPB 256
#define BSH 7                 // nodes per bucket = 128
#define BNODES 128
#define EPW 8192              // edges per workgroup in passA

// ---------------- small utils ----------------

__global__ void k_zero(int* __restrict__ p, int n) {
    int i = blockIdx.x * blockDim.x + threadIdx.x;
    if (i < n) p[i] = 0;
}

// ---------------- bucket histogram (LDS-aggregated) ----------------

__global__ void k_hist(const int* __restrict__ dst, int* __restrict__ bcnt, int E, int NB) {
    extern __shared__ int cnt[];
    for (int i = threadIdx.x; i < NB; i += TPB) cnt[i] = 0;
    __syncthreads();
    int per = (E + gridDim.x - 1) / gridDim.x;
    int s = blockIdx.x * per;
    int e = min(E, s + per);
    for (int i = s + threadIdx.x; i < e; i += TPB)
        atomicAdd(&cnt[dst[i] >> BSH], 1);
    __syncthreads();
    for (int i = threadIdx.x; i < NB; i += TPB)
        if (cnt[i]) atomicAdd(&bcnt[i], cnt[i]);
}

// ---------------- exclusive scan of bucket counts (1 wg) ----------------

__global__ void k_scanb(const int* __restrict__ bcnt, int* __restrict__ bbase,
                        int* __restrict__ cursor, int NB) {
    __shared__ int sh[TPB];
    __shared__ int carry;
    if (threadIdx.x == 0) carry = 0;
    __syncthreads();
    for (int c0 = 0; c0 < NB; c0 += TPB) {
        int i = c0 + threadIdx.x;
        int v = (i < NB) ? bcnt[i] : 0;
        sh[threadIdx.x] = v;
        __syncthreads();
        for (int off = 1; off < TPB; off <<= 1) {
            int t = (threadIdx.x >= off) ? sh[threadIdx.x - off] : 0;
            __syncthreads();
            sh[threadIdx.x] += t;
            __syncthreads();
        }
        int total = sh[TPB - 1];
        int ex = carry + sh[threadIdx.x] - v;
        __syncthreads();
        if (threadIdx.x == 0) carry += total;
        __syncthreads();
        if (i < NB) { bbase[i] = ex; cursor[i] = ex; }
    }
    if (threadIdx.x == 0) bbase[NB] = carry;  // == E
}

// ---------------- pass A: partition edges into buckets, packed (src<<7|dstLocal) ----------------

__global__ void k_passA(const int* __restrict__ src, const int* __restrict__ dst,
                        int* __restrict__ cursor, unsigned* __restrict__ packed,
                        int E, int NB) {
    extern __shared__ int sh[];
    int* cnt = sh;          // [NB]
    int* wbase = sh + NB;   // [NB]
    for (int i = threadIdx.x; i < NB; i += TPB) cnt[i] = 0;
    __syncthreads();
    int base = blockIdx.x * EPW;
    int eend = min(E, base + EPW);
    for (int i = base + threadIdx.x; i < eend; i += TPB)
        atomicAdd(&cnt[dst[i] >> BSH], 1);
    __syncthreads();
    for (int b = threadIdx.x; b < NB; b += TPB) {
        int c = cnt[b];
        if (c) wbase[b] = atomicAdd(&cursor[b], c);
        cnt[b] = 0;
    }
    __syncthreads();
    for (int i = base + threadIdx.x; i < eend; i += TPB) {
        int d = dst[i];
        int b = d >> BSH;
        int r = atomicAdd(&cnt[b], 1);
        packed[wbase[b] + r] = ((unsigned)src[i] << BSH) | (unsigned)(d & (BNODES - 1));
    }
}

// ---------------- per-bucket: degree->dis, then hs1 = (x@W1)*dis ----------------

__global__ void k_prep(const unsigned* __restrict__ packed, const int* __restrict__ bbase,
                       const float* __restrict__ x, const float* __restrict__ W1,
                       float* __restrict__ dis, float* __restrict__ hs1, int N) {
    __shared__ int cnt[BNODES];
    __shared__ float w[64];
    __shared__ float disl[BNODES];
    int b = blockIdx.x;
    int node0 = b << BSH;
    if (threadIdx.x < BNODES) cnt[threadIdx.x] = 0;
    if (threadIdx.x < 64) w[threadIdx.x] = W1[threadIdx.x];
    __syncthreads();
    int e0 = bbase[b], e1 = bbase[b + 1];
    for (int i = e0 + threadIdx.x; i < e1; i += TPB)
        atomicAdd(&cnt[packed[i] & (BNODES - 1)], 1);
    __syncthreads();
    if (threadIdx.x < BNODES && node0 + threadIdx.x < N) {
        float di = rsqrtf((float)(cnt[threadIdx.x] + 1));  // +1 self-loop
        disl[threadIdx.x] = di;
        dis[node0 + threadIdx.x] = di;
    }
    __syncthreads();
    int v = threadIdx.x >> 1;
    int half = threadIdx.x & 1;
    if (v < BNODES && node0 + v < N) {
        float4 xv = ((const float4*)x)[node0 + v];
        float di = disl[v];
#pragma unroll
        for (int jj = 0; jj < 8; jj++) {
            int j = half * 8 + jj;
            float h = xv.x * w[j] + xv.y * w[16 + j] + xv.z * w[32 + j] + xv.w * w[48 + j];
            hs1[(size_t)(node0 + v) * 16 + j] = h * di;
        }
    }
}

// ---------------- layer-1 aggregate (LDS acc, high-MLP) + fused layer-2 linear ----------------

#define ASTRIDE 17  // pad to break power-of-2 bank strides
#define U1 8        // unroll (independent gathers in flight per lane)

__global__ void k_agg1b(const unsigned* __restrict__ packed, const int* __restrict__ bbase,
                        const float* __restrict__ hs1, const float* __restrict__ dis,
                        const float* __restrict__ b1, const float* __restrict__ W2,
                        float* __restrict__ hs2, int N) {
    __shared__ float acc[BNODES * ASTRIDE];
    __shared__ float w2[32];
    __shared__ float bb[16];
    if (threadIdx.x < 32) w2[threadIdx.x] = W2[threadIdx.x];
    if (threadIdx.x < 16) bb[threadIdx.x] = b1[threadIdx.x];
    for (int i = threadIdx.x; i < BNODES * ASTRIDE; i += TPB) acc[i] = 0.0f;
    __syncthreads();
    int b = blockIdx.x;
    int node0 = b << BSH;
    int e0 = bbase[b], e1 = bbase[b + 1];
    // 4-lane groups: each group handles one edge via a float4 gather
    int gg = threadIdx.x >> 2;   // 64 groups
    int f4 = threadIdx.x & 3;    // float4 slot
    const int GS = 64;           // group stride in edges
    int e = e0 + gg;
    for (; e + (U1 - 1) * GS < e1; e += U1 * GS) {
        unsigned pk[U1];
#pragma unroll
        for (int u = 0; u < U1; u++) pk[u] = packed[e + u * GS];
        float4 m[U1];
#pragma unroll
        for (int u = 0; u < U1; u++)
            m[u] = ((const float4*)hs1)[(size_t)(pk[u] >> BSH) * 4 + f4];
#pragma unroll
        for (int u = 0; u < U1; u++) {
            int dl = pk[u] & (BNODES - 1);
            float* a = &acc[dl * ASTRIDE + f4 * 4];
            atomicAdd(a + 0, m[u].x);
            atomicAdd(a + 1, m[u].y);
            atomicAdd(a + 2, m[u].z);
            atomicAdd(a + 3, m[u].w);
        }
    }
    for (; e < e1; e += GS) {
        unsigned pk = packed[e];
        float4 m = ((const float4*)hs1)[(size_t)(pk >> BSH) * 4 + f4];
        int dl = pk & (BNODES - 1);
        float* a = &acc[dl * ASTRIDE + f4 * 4];
        atomicAdd(a + 0, m.x);
        atomicAdd(a + 1, m.y);
        atomicAdd(a + 2, m.z);
        atomicAdd(a + 3, m.w);
    }
    __syncthreads();
    int t = threadIdx.x;
    if (t < BNODES && node0 + t < N) {
        float di = dis[node0 + t];
        float s0 = 0.f, s1 = 0.f;
#pragma unroll
        for (int j = 0; j < 16; j++) {
            float r = (acc[t * ASTRIDE + j] + hs1[(size_t)(node0 + t) * 16 + j]) * di + bb[j];
            r = fmaxf(r, 0.0f);
            s0 += r * w2[2 * j];
            s1 += r * w2[2 * j + 1];
        }
        ((float2*)hs2)[node0 + t] = make_float2(s0 * di, s1 * di);
    }
}

// ---------------- layer-2 aggregate (LDS acc, high-MLP) + final bias -> out ----------------

#define U2 8

__global__ void k_agg2b(const unsigned* __restrict__ packed, const int* __restrict__ bbase,
                        const float* __restrict__ hs2, const float* __restrict__ dis,
                        const float* __restrict__ b2, float* __restrict__ out, int N) {
    __shared__ float acc[BNODES * 2];
    for (int i = threadIdx.x; i < BNODES * 2; i += TPB) acc[i] = 0.0f;
    __syncthreads();
    int b = blockIdx.x;
    int node0 = b << BSH;
    int e0 = bbase[b], e1 = bbase[b + 1];
    // one edge per lane, float2 gather
    int e = e0 + threadIdx.x;
    for (; e + (U2 - 1) * TPB < e1; e += U2 * TPB) {
        unsigned pk[U2];
#pragma unroll
        for (int u = 0; u < U2; u++) pk[u] = packed[e + u * TPB];
        float2 m[U2];
#pragma unroll
        for (int u = 0; u < U2; u++)
            m[u] = ((const float2*)hs2)[(size_t)(pk[u] >> BSH)];
#pragma unroll
        for (int u = 0; u < U2; u++) {
            int dl = pk[u] & (BNODES - 1);
            atomicAdd(&acc[dl * 2 + 0], m[u].x);
            atomicAdd(&acc[dl * 2 + 1], m[u].y);
        }
    }
    for (; e < e1; e += TPB) {
        unsigned pk = packed[e];
        float2 m = ((const float2*)hs2)[(size_t)(pk >> BSH)];
        int dl = pk & (BNODES - 1);
        atomicAdd(&acc[dl * 2 + 0], m.x);
        atomicAdd(&acc[dl * 2 + 1], m.y);
    }
    __syncthreads();
    int v = threadIdx.x >> 1;
    int f = threadIdx.x & 1;
    if (v < BNODES && node0 + v < N) {
        float r = (acc[v * 2 + f] + hs2[(size_t)(node0 + v) * 2 + f]) * dis[node0 + v] + b2[f];
        out[(size_t)(node0 + v) * 2 + f] = r;
    }
}

// ---------------- fallback (R1 atomic pipeline) ----------------

__global__ void k_deg_fb(const int* __restrict__ dst, int* __restrict__ deg, int E) {
    int i = blockIdx.x * blockDim.x + threadIdx.x;
    if (i < E) atomicAdd(&deg[dst[i]], 1);
}
__global__ void k_dis_fb(const int* __restrict__ deg, float* __restrict__ dis, int N) {
    int v = blockIdx.x * blockDim.x + threadIdx.x;
    if (v < N) dis[v] = rsqrtf((float)(deg[v] + 1));
}
__global__ void k_lin1_fb(const float* __restrict__ x, const float* __restrict__ W1,
                          const float* __restrict__ dis, float* __restrict__ hs1,
                          float* __restrict__ agg1, int N) {
    __shared__ float w[64];
    if (threadIdx.x < 64) w[threadIdx.x] = W1[threadIdx.x];
    __syncthreads();
    int v = blockIdx.x * blockDim.x + threadIdx.x;
    if (v >= N) return;
    float4 xv = ((const float4*)x)[v];
    float d = dis[v];
#pragma unroll
    for (int j = 0; j < 16; j++) {
        float h = (xv.x * w[j] + xv.y * w[16 + j] + xv.z * w[32 + j] + xv.w * w[48 + j]) * d;
        hs1[v * 16 + j] = h;
        agg1[v * 16 + j] = h;
    }
}
__global__ void k_scat1_fb(const int* __restrict__ src, const int* __restrict__ dst,
                           const float* __restrict__ hs1, float* __restrict__ agg1, int E4) {
    int t = blockIdx.x * blockDim.x + threadIdx.x;
    if (t >= E4) return;
    int e = t >> 2, q = t & 3;
    int s = src[e], d = dst[e];
    float4 m = ((const float4*)hs1)[s * 4 + q];
    float* a = agg1 + (size_t)d * 16 + q * 4;
    atomicAdd(a + 0, m.x); atomicAdd(a + 1, m.y);
    atomicAdd(a + 2, m.z); atomicAdd(a + 3, m.w);
}
__global__ void k_lin2_fb(const float* __restrict__ agg1, const float* __restrict__ dis,
                          const float* __restrict__ b1, const float* __restrict__ W2,
                          float* __restrict__ hs2, float* __restrict__ agg2, int N) {
    __shared__ float w[32];
    __shared__ float bb[16];
    if (threadIdx.x < 32) w[threadIdx.x] = W2[threadIdx.x];
    if (threadIdx.x < 16) bb[threadIdx.x] = b1[threadIdx.x];
    __syncthreads();
    int v = blockIdx.x * blockDim.x + threadIdx.x;
    if (v >= N) return;
    float d = dis[v];
    float a0 = 0.f, a1 = 0.f;
#pragma unroll
    for (int k = 0; k < 16; k++) {
        float r = fmaxf(agg1[v * 16 + k] * d + bb[k], 0.0f);
        a0 += r * w[k * 2 + 0];
        a1 += r * w[k * 2 + 1];
    }
    float2 hv = make_float2(a0 * d, a1 * d);
    ((float2*)hs2)[v] = hv;
    ((float2*)agg2)[v] = hv;
}
__global__ void k_scat2_fb(const int* __restrict__ src, const int* __restrict__ dst,
                           const float* __restrict__ hs2, float* __restrict__ agg2, int E) {
    int e = blockIdx.x * blockDim.x + threadIdx.x;
    if (e >= E) return;
    int s = src[e], d = dst[e];
    float2 m = ((const float2*)hs2)[s];
    atomicAdd(&agg2[d * 2 + 0], m.x);
    atomicAdd(&agg2[d * 2 + 1], m.y);
}
__global__ void k_out_fb(const float* __restrict__ agg2, const float* __restrict__ dis,
                         const float* __restrict__ b2, float* __restrict__ out, int N) {
    int v = blockIdx.x * blockDim.x + threadIdx.x;
    if (v >= N) return;
    float d = dis[v];
    out[v * 2 + 0] = agg2[v * 2 + 0] * d + b2[0];
    out[v * 2 + 1] = agg2[v * 2 + 1] * d + b2[1];
}

// ---------------- launch ----------------

extern "C" void kernel_launch(void* const* d_in, const int* in_sizes, int n_in,
                              void* d_out, int out_size, void* d_ws, size_t ws_size,
                              hipStream_t stream) {
    const float* x  = (const float*)d_in[0];
    const int*   ei = (const int*)d_in[1];
    const float* W1 = (const float*)d_in[2];
    const float* b1 = (const float*)d_in[3];
    const float* W2 = (const float*)d_in[4];
    const float* b2 = (const float*)d_in[5];

    const int N = in_sizes[0] / 4;   // 100000
    const int E = in_sizes[1] / 2;   // 6400000
    const int* src = ei;
    const int* dst = ei + E;
    float* outp = (float*)d_out;

    auto align = [](size_t v) { return (v + 255) & ~(size_t)255; };
    const int NB = (N + BNODES - 1) >> BSH;

    size_t need = align((size_t)E * 4)            /* packed */
                + align((size_t)N * 4)            /* dis */
                + align((size_t)N * 16 * 4)       /* hs1 */
                + align((size_t)N * 2 * 4)        /* hs2 */
                + align((size_t)NB * 4) * 2       /* bcnt, cursor */
                + align((size_t)(NB + 1) * 4);    /* bbase */

    if (ws_size >= need && (size_t)N <= (1u << 25) && NB <= 4096) {
        char* ws = (char*)d_ws;
        unsigned* packed = (unsigned*)ws; ws += align((size_t)E * 4);
        float* dis  = (float*)ws; ws += align((size_t)N * 4);
        float* hs1  = (float*)ws; ws += align((size_t)N * 16 * 4);
        float* hs2  = (float*)ws; ws += align((size_t)N * 2 * 4);
        int* bcnt   = (int*)ws;   ws += align((size_t)NB * 4);
        int* cursor = (int*)ws;   ws += align((size_t)NB * 4);
        int* bbase  = (int*)ws;   ws += align((size_t)(NB + 1) * 4);

        int gA = (E + EPW - 1) / EPW;

        k_zero<<<(NB + TPB - 1) / TPB, TPB, 0, stream>>>(bcnt, NB);
        k_hist<<<512, TPB, (size_t)NB * 4, stream>>>(dst, bcnt, E, NB);
        k_scanb<<<1, TPB, 0, stream>>>(bcnt, bbase, cursor, NB);
        k_passA<<<gA, TPB, (size_t)NB * 8, stream>>>(src, dst, cursor, packed, E, NB);
        k_prep<<<NB, TPB, 0, stream>>>(packed, bbase, x, W1, dis, hs1, N);
        k_agg1b<<<NB, TPB, 0, stream>>>(packed, bbase, hs1, dis, b1, W2, hs2, N);
        k_agg2b<<<NB, TPB, 0, stream>>>(packed, bbase, hs2, dis, b2, outp, N);
    } else {
        // fallback: R1 atomic-scatter pipeline
        char* ws = (char*)d_ws;
        int*   deg  = (int*)ws;   ws += align((size_t)N * 4);
        float* dis  = (float*)ws; ws += align((size_t)N * 4);
        float* hs1  = (float*)ws; ws += align((size_t)N * 16 * 4);
        float* agg1 = (float*)ws; ws += align((size_t)N * 16 * 4);
        float* hs2  = (float*)ws; ws += align((size_t)N * 2 * 4);
        float* agg2 = (float*)ws; ws += align((size_t)N * 2 * 4);
        int gN = (N + TPB - 1) / TPB;
        int gE = (E + TPB - 1) / TPB;
        int gE4 = ((size_t)E * 4 + TPB - 1) / TPB;

        k_zero<<<gN, TPB, 0, stream>>>(deg, N);
        k_deg_fb<<<gE, TPB, 0, stream>>>(dst, deg, E);
        k_dis_fb<<<gN, TPB, 0, stream>>>(deg, dis, N);
        k_lin1_fb<<<gN, TPB, 0, stream>>>(x, W1, dis, hs1, agg1, N);
        k_scat1_fb<<<gE4, TPB, 0, stream>>>(src, dst, hs1, agg1, E * 4);
        k_lin2_fb<<<gN, TPB, 0, stream>>>(agg1, dis, b1, W2, hs2, agg2, N);
        k_scat2_fb<<<gE, TPB, 0, stream>>>(src, dst, hs2, agg2, E);
        k_out_fb<<<gN, TPB, 0, stream>>>(agg2, dis, b2, outp, N);
    }
}

// Round 5
// 878.148 us; speedup vs baseline: 2.5508x; 1.1356x over previous
//
#include <hip/hip_runtime.h>

#define TPB 256
#define BSH 7                 // nodes per bucket = 128
#define BNODES 128
#define EPW 8192              // edges per workgroup in passA
#define ASTRIDE 17            // LDS pad to spread atomic banks

// ---------------- small utils ----------------

__global__ void k_zero(int* __restrict__ p, int n) {
    int i = blockIdx.x * blockDim.x + threadIdx.x;
    if (i < n) p[i] = 0;
}

// ---------------- bucket histogram (LDS-aggregated) ----------------

__global__ void k_hist(const int* __restrict__ dst, int* __restrict__ bcnt, int E, int NB) {
    extern __shared__ int cnt[];
    for (int i = threadIdx.x; i < NB; i += TPB) cnt[i] = 0;
    __syncthreads();
    int per = (E + gridDim.x - 1) / gridDim.x;
    int s = blockIdx.x * per;
    int e = min(E, s + per);
    for (int i = s + threadIdx.x; i < e; i += TPB)
        atomicAdd(&cnt[dst[i] >> BSH], 1);
    __syncthreads();
    for (int i = threadIdx.x; i < NB; i += TPB)
        if (cnt[i]) atomicAdd(&bcnt[i], cnt[i]);
}

// ---------------- exclusive scan of bucket counts (1 wg) ----------------

__global__ void k_scanb(const int* __restrict__ bcnt, int* __restrict__ bbase,
                        int* __restrict__ cursor, int NB) {
    __shared__ int sh[TPB];
    __shared__ int carry;
    if (threadIdx.x == 0) carry = 0;
    __syncthreads();
    for (int c0 = 0; c0 < NB; c0 += TPB) {
        int i = c0 + threadIdx.x;
        int v = (i < NB) ? bcnt[i] : 0;
        sh[threadIdx.x] = v;
        __syncthreads();
        for (int off = 1; off < TPB; off <<= 1) {
            int t = (threadIdx.x >= off) ? sh[threadIdx.x - off] : 0;
            __syncthreads();
            sh[threadIdx.x] += t;
            __syncthreads();
        }
        int total = sh[TPB - 1];
        int ex = carry + sh[threadIdx.x] - v;
        __syncthreads();
        if (threadIdx.x == 0) carry += total;
        __syncthreads();
        if (i < NB) { bbase[i] = ex; cursor[i] = ex; }
    }
    if (threadIdx.x == 0) bbase[NB] = carry;  // == E
}

// ---------------- pass A: partition edges into buckets, packed (src<<7|dstLocal) ----------------

__global__ void k_passA(const int* __restrict__ src, const int* __restrict__ dst,
                        int* __restrict__ cursor, unsigned* __restrict__ packed,
                        int E, int NB) {
    extern __shared__ int sh[];
    int* cnt = sh;          // [NB]
    int* wbase = sh + NB;   // [NB]
    for (int i = threadIdx.x; i < NB; i += TPB) cnt[i] = 0;
    __syncthreads();
    int base = blockIdx.x * EPW;
    int eend = min(E, base + EPW);
    for (int i = base + threadIdx.x; i < eend; i += TPB)
        atomicAdd(&cnt[dst[i] >> BSH], 1);
    __syncthreads();
    for (int b = threadIdx.x; b < NB; b += TPB) {
        int c = cnt[b];
        if (c) wbase[b] = atomicAdd(&cursor[b], c);
        cnt[b] = 0;
    }
    __syncthreads();
    for (int i = base + threadIdx.x; i < eend; i += TPB) {
        int d = dst[i];
        int b = d >> BSH;
        int r = atomicAdd(&cnt[b], 1);
        packed[wbase[b] + r] = ((unsigned)src[i] << BSH) | (unsigned)(d & (BNODES - 1));
    }
}

// ---------------- per-bucket: degree->dis, then hs1 = (x@W1)*dis ----------------

__global__ void k_prep(const unsigned* __restrict__ packed, const int* __restrict__ bbase,
                       const float* __restrict__ x, const float* __restrict__ W1,
                       float* __restrict__ dis, float* __restrict__ hs1, int N) {
    __shared__ int cnt[BNODES];
    __shared__ float w[64];
    __shared__ float disl[BNODES];
    int b = blockIdx.x;
    int node0 = b << BSH;
    if (threadIdx.x < BNODES) cnt[threadIdx.x] = 0;
    if (threadIdx.x < 64) w[threadIdx.x] = W1[threadIdx.x];
    __syncthreads();
    int e0 = bbase[b], e1 = bbase[b + 1];
    for (int i = e0 + threadIdx.x; i < e1; i += TPB)
        atomicAdd(&cnt[packed[i] & (BNODES - 1)], 1);
    __syncthreads();
    if (threadIdx.x < BNODES && node0 + threadIdx.x < N) {
        float di = rsqrtf((float)(cnt[threadIdx.x] + 1));  // +1 self-loop
        disl[threadIdx.x] = di;
        dis[node0 + threadIdx.x] = di;
    }
    __syncthreads();
    int v = threadIdx.x >> 1;
    int half = threadIdx.x & 1;
    if (v < BNODES && node0 + v < N) {
        float4 xv = ((const float4*)x)[node0 + v];
        float di = disl[v];
#pragma unroll
        for (int jj = 0; jj < 8; jj++) {
            int j = half * 8 + jj;
            float h = xv.x * w[j] + xv.y * w[16 + j] + xv.z * w[32 + j] + xv.w * w[48 + j];
            hs1[(size_t)(node0 + v) * 16 + j] = h * di;
        }
    }
}

// ---------------- layer-1 edge pass: sub-block partial accumulators ----------------

#define U1 4

__global__ void k_agg1p(const unsigned* __restrict__ packed, const int* __restrict__ bbase,
                        const float* __restrict__ hs1, float* __restrict__ partial1, int S1) {
    __shared__ float acc[BNODES * ASTRIDE];
    for (int i = threadIdx.x; i < BNODES * ASTRIDE; i += TPB) acc[i] = 0.0f;
    __syncthreads();
    int b = blockIdx.x / S1;
    int s = blockIdx.x - b * S1;
    int e0 = bbase[b], e1 = bbase[b + 1];
    int len = e1 - e0;
    int ce0 = e0 + (int)((long long)len * s / S1);
    int ce1 = e0 + (int)((long long)len * (s + 1) / S1);
    int gg = threadIdx.x >> 2;   // 64 groups of 4 lanes
    int f4 = threadIdx.x & 3;
    const int GS = 64;
    int e = ce0 + gg;
    for (; e + (U1 - 1) * GS < ce1; e += U1 * GS) {
        unsigned pk[U1];
#pragma unroll
        for (int u = 0; u < U1; u++) pk[u] = packed[e + u * GS];
        float4 m[U1];
#pragma unroll
        for (int u = 0; u < U1; u++)
            m[u] = ((const float4*)hs1)[(size_t)(pk[u] >> BSH) * 4 + f4];
#pragma unroll
        for (int u = 0; u < U1; u++) {
            int dl = pk[u] & (BNODES - 1);
            float* a = &acc[dl * ASTRIDE + f4 * 4];
            atomicAdd(a + 0, m[u].x);
            atomicAdd(a + 1, m[u].y);
            atomicAdd(a + 2, m[u].z);
            atomicAdd(a + 3, m[u].w);
        }
    }
    for (; e < ce1; e += GS) {
        unsigned pk = packed[e];
        float4 m = ((const float4*)hs1)[(size_t)(pk >> BSH) * 4 + f4];
        int dl = pk & (BNODES - 1);
        float* a = &acc[dl * ASTRIDE + f4 * 4];
        atomicAdd(a + 0, m.x);
        atomicAdd(a + 1, m.y);
        atomicAdd(a + 2, m.z);
        atomicAdd(a + 3, m.w);
    }
    __syncthreads();
    float* p = partial1 + (size_t)blockIdx.x * (BNODES * 16);
    for (int i = threadIdx.x; i < BNODES * 16; i += TPB)
        p[i] = acc[(i >> 4) * ASTRIDE + (i & 15)];
}

// ---------------- layer-1 combine + fused layer-2 linear ----------------

__global__ void k_comb1(const float* __restrict__ partial1, const float* __restrict__ hs1,
                        const float* __restrict__ dis, const float* __restrict__ b1,
                        const float* __restrict__ W2, float* __restrict__ hs2,
                        int S1, int N) {
    __shared__ float w2[32];
    __shared__ float bb[16];
    if (threadIdx.x < 32) w2[threadIdx.x] = W2[threadIdx.x];
    if (threadIdx.x < 16) bb[threadIdx.x] = b1[threadIdx.x];
    __syncthreads();
    int b = blockIdx.x;
    int node0 = b << BSH;
    int t = threadIdx.x;
    if (t >= BNODES || node0 + t >= N) return;
    float sum[16];
    const float4* selfp = (const float4*)(hs1 + (size_t)(node0 + t) * 16);
#pragma unroll
    for (int q = 0; q < 4; q++) {
        float4 v = selfp[q];
        sum[q * 4 + 0] = v.x; sum[q * 4 + 1] = v.y;
        sum[q * 4 + 2] = v.z; sum[q * 4 + 3] = v.w;
    }
    for (int s = 0; s < S1; s++) {
        const float4* q4 = (const float4*)(partial1 + ((size_t)b * S1 + s) * (BNODES * 16) + t * 16);
#pragma unroll
        for (int q = 0; q < 4; q++) {
            float4 v = q4[q];
            sum[q * 4 + 0] += v.x; sum[q * 4 + 1] += v.y;
            sum[q * 4 + 2] += v.z; sum[q * 4 + 3] += v.w;
        }
    }
    float di = dis[node0 + t];
    float s0 = 0.f, s1 = 0.f;
#pragma unroll
    for (int j = 0; j < 16; j++) {
        float r = fmaxf(sum[j] * di + bb[j], 0.0f);
        s0 += r * w2[2 * j];
        s1 += r * w2[2 * j + 1];
    }
    ((float2*)hs2)[node0 + t] = make_float2(s0 * di, s1 * di);
}

// ---------------- layer-2 edge pass: sub-block partial accumulators ----------------

#define U2 4

__global__ void k_agg2p(const unsigned* __restrict__ packed, const int* __restrict__ bbase,
                        const float* __restrict__ hs2, float* __restrict__ partial2, int S2) {
    __shared__ float acc[BNODES * 2];
    for (int i = threadIdx.x; i < BNODES * 2; i += TPB) acc[i] = 0.0f;
    __syncthreads();
    int b = blockIdx.x / S2;
    int s = blockIdx.x - b * S2;
    int e0 = bbase[b], e1 = bbase[b + 1];
    int len = e1 - e0;
    int ce0 = e0 + (int)((long long)len * s / S2);
    int ce1 = e0 + (int)((long long)len * (s + 1) / S2);
    int gg = threadIdx.x >> 1;   // 128 groups of 2 lanes
    int f = threadIdx.x & 1;
    const int GS = 128;
    int e = ce0 + gg;
    for (; e + (U2 - 1) * GS < ce1; e += U2 * GS) {
        unsigned pk[U2];
#pragma unroll
        for (int u = 0; u < U2; u++) pk[u] = packed[e + u * GS];
        float m[U2];
#pragma unroll
        for (int u = 0; u < U2; u++)
            m[u] = hs2[(size_t)(pk[u] >> BSH) * 2 + f];
#pragma unroll
        for (int u = 0; u < U2; u++)
            atomicAdd(&acc[(pk[u] & (BNODES - 1)) * 2 + f], m[u]);
    }
    for (; e < ce1; e += GS) {
        unsigned pk = packed[e];
        float m = hs2[(size_t)(pk >> BSH) * 2 + f];
        atomicAdd(&acc[(pk & (BNODES - 1)) * 2 + f], m);
    }
    __syncthreads();
    float* p = partial2 + (size_t)blockIdx.x * (BNODES * 2);
    if (threadIdx.x < BNODES * 2) p[threadIdx.x] = acc[threadIdx.x];
}

// ---------------- layer-2 combine + final bias -> out ----------------

__global__ void k_comb2(const float* __restrict__ partial2, const float* __restrict__ hs2,
                        const float* __restrict__ dis, const float* __restrict__ b2,
                        float* __restrict__ out, int S2, int N) {
    int b = blockIdx.x;
    int node0 = b << BSH;
    int v = threadIdx.x >> 1;
    int f = threadIdx.x & 1;
    if (v >= BNODES || node0 + v >= N) return;
    float sum = hs2[(size_t)(node0 + v) * 2 + f];  // self-loop
    for (int s = 0; s < S2; s++)
        sum += partial2[((size_t)b * S2 + s) * (BNODES * 2) + v * 2 + f];
    out[(size_t)(node0 + v) * 2 + f] = sum * dis[node0 + v] + b2[f];
}

// ---------------- fallback (R1 atomic pipeline) ----------------

__global__ void k_deg_fb(const int* __restrict__ dst, int* __restrict__ deg, int E) {
    int i = blockIdx.x * blockDim.x + threadIdx.x;
    if (i < E) atomicAdd(&deg[dst[i]], 1);
}
__global__ void k_dis_fb(const int* __restrict__ deg, float* __restrict__ dis, int N) {
    int v = blockIdx.x * blockDim.x + threadIdx.x;
    if (v < N) dis[v] = rsqrtf((float)(deg[v] + 1));
}
__global__ void k_lin1_fb(const float* __restrict__ x, const float* __restrict__ W1,
                          const float* __restrict__ dis, float* __restrict__ hs1,
                          float* __restrict__ agg1, int N) {
    __shared__ float w[64];
    if (threadIdx.x < 64) w[threadIdx.x] = W1[threadIdx.x];
    __syncthreads();
    int v = blockIdx.x * blockDim.x + threadIdx.x;
    if (v >= N) return;
    float4 xv = ((const float4*)x)[v];
    float d = dis[v];
#pragma unroll
    for (int j = 0; j < 16; j++) {
        float h = (xv.x * w[j] + xv.y * w[16 + j] + xv.z * w[32 + j] + xv.w * w[48 + j]) * d;
        hs1[v * 16 + j] = h;
        agg1[v * 16 + j] = h;
    }
}
__global__ void k_scat1_fb(const int* __restrict__ src, const int* __restrict__ dst,
                           const float* __restrict__ hs1, float* __restrict__ agg1, int E4) {
    int t = blockIdx.x * blockDim.x + threadIdx.x;
    if (t >= E4) return;
    int e = t >> 2, q = t & 3;
    int s = src[e], d = dst[e];
    float4 m = ((const float4*)hs1)[s * 4 + q];
    float* a = agg1 + (size_t)d * 16 + q * 4;
    atomicAdd(a + 0, m.x); atomicAdd(a + 1, m.y);
    atomicAdd(a + 2, m.z); atomicAdd(a + 3, m.w);
}
__global__ void k_lin2_fb(const float* __restrict__ agg1, const float* __restrict__ dis,
                          const float* __restrict__ b1, const float* __restrict__ W2,
                          float* __restrict__ hs2, float* __restrict__ agg2, int N) {
    __shared__ float w[32];
    __shared__ float bb[16];
    if (threadIdx.x < 32) w[threadIdx.x] = W2[threadIdx.x];
    if (threadIdx.x < 16) bb[threadIdx.x] = b1[threadIdx.x];
    __syncthreads();
    int v = blockIdx.x * blockDim.x + threadIdx.x;
    if (v >= N) return;
    float d = dis[v];
    float a0 = 0.f, a1 = 0.f;
#pragma unroll
    for (int k = 0; k < 16; k++) {
        float r = fmaxf(agg1[v * 16 + k] * d + bb[k], 0.0f);
        a0 += r * w[k * 2 + 0];
        a1 += r * w[k * 2 + 1];
    }
    float2 hv = make_float2(a0 * d, a1 * d);
    ((float2*)hs2)[v] = hv;
    ((float2*)agg2)[v] = hv;
}
__global__ void k_scat2_fb(const int* __restrict__ src, const int* __restrict__ dst,
                           const float* __restrict__ hs2, float* __restrict__ agg2, int E) {
    int e = blockIdx.x * blockDim.x + threadIdx.x;
    if (e >= E) return;
    int s = src[e], d = dst[e];
    float2 m = ((const float2*)hs2)[s];
    atomicAdd(&agg2[d * 2 + 0], m.x);
    atomicAdd(&agg2[d * 2 + 1], m.y);
}
__global__ void k_out_fb(const float* __restrict__ agg2, const float* __restrict__ dis,
                         const float* __restrict__ b2, float* __restrict__ out, int N) {
    int v = blockIdx.x * blockDim.x + threadIdx.x;
    if (v >= N) return;
    float d = dis[v];
    out[v * 2 + 0] = agg2[v * 2 + 0] * d + b2[0];
    out[v * 2 + 1] = agg2[v * 2 + 1] * d + b2[1];
}

// ---------------- launch ----------------

extern "C" void kernel_launch(void* const* d_in, const int* in_sizes, int n_in,
                              void* d_out, int out_size, void* d_ws, size_t ws_size,
                              hipStream_t stream) {
    const float* x  = (const float*)d_in[0];
    const int*   ei = (const int*)d_in[1];
    const float* W1 = (const float*)d_in[2];
    const float* b1 = (const float*)d_in[3];
    const float* W2 = (const float*)d_in[4];
    const float* b2 = (const float*)d_in[5];

    const int N = in_sizes[0] / 4;   // 100000
    const int E = in_sizes[1] / 2;   // 6400000
    const int* src = ei;
    const int* dst = ei + E;
    float* outp = (float*)d_out;

    auto align = [](size_t v) { return (v + 255) & ~(size_t)255; };
    const int NB = (N + BNODES - 1) >> BSH;

    size_t base_need = align((size_t)E * 4)          /* packed */
                     + align((size_t)N * 4)          /* dis */
                     + align((size_t)N * 16 * 4)     /* hs1 */
                     + align((size_t)N * 2 * 4)      /* hs2 */
                     + align((size_t)NB * 4) * 2     /* bcnt, cursor */
                     + align((size_t)(NB + 1) * 4);  /* bbase */
    auto part_need = [&](int S1, int S2) {
        return align((size_t)NB * S1 * BNODES * 16 * 4)
             + align((size_t)NB * S2 * BNODES * 2 * 4);
    };

    int S1 = 4, S2 = 4;
    if (base_need + part_need(S1, S2) > ws_size) { S1 = 2; S2 = 2; }
    if (base_need + part_need(S1, S2) > ws_size) { S1 = 1; S2 = 1; }

    if (base_need + part_need(S1, S2) <= ws_size && (size_t)N <= (1u << 25) && NB <= 4096) {
        char* ws = (char*)d_ws;
        unsigned* packed = (unsigned*)ws; ws += align((size_t)E * 4);
        float* dis  = (float*)ws; ws += align((size_t)N * 4);
        float* hs1  = (float*)ws; ws += align((size_t)N * 16 * 4);
        float* hs2  = (float*)ws; ws += align((size_t)N * 2 * 4);
        int* bcnt   = (int*)ws;   ws += align((size_t)NB * 4);
        int* cursor = (int*)ws;   ws += align((size_t)NB * 4);
        int* bbase  = (int*)ws;   ws += align((size_t)(NB + 1) * 4);
        float* partial1 = (float*)ws; ws += align((size_t)NB * S1 * BNODES * 16 * 4);
        float* partial2 = (float*)ws; ws += align((size_t)NB * S2 * BNODES * 2 * 4);

        int gA = (E + EPW - 1) / EPW;

        k_zero<<<(NB + TPB - 1) / TPB, TPB, 0, stream>>>(bcnt, NB);
        k_hist<<<512, TPB, (size_t)NB * 4, stream>>>(dst, bcnt, E, NB);
        k_scanb<<<1, TPB, 0, stream>>>(bcnt, bbase, cursor, NB);
        k_passA<<<gA, TPB, (size_t)NB * 8, stream>>>(src, dst, cursor, packed, E, NB);
        k_prep<<<NB, TPB, 0, stream>>>(packed, bbase, x, W1, dis, hs1, N);
        k_agg1p<<<NB * S1, TPB, 0, stream>>>(packed, bbase, hs1, partial1, S1);
        k_comb1<<<NB, TPB, 0, stream>>>(partial1, hs1, dis, b1, W2, hs2, S1, N);
        k_agg2p<<<NB * S2, TPB, 0, stream>>>(packed, bbase, hs2, partial2, S2);
        k_comb2<<<NB, TPB, 0, stream>>>(partial2, hs2, dis, b2, outp, S2, N);
    } else {
        // fallback: R1 atomic-scatter pipeline
        char* ws = (char*)d_ws;
        int*   deg  = (int*)ws;   ws += align((size_t)N * 4);
        float* dis  = (float*)ws; ws += align((size_t)N * 4);
        float* hs1  = (float*)ws; ws += align((size_t)N * 16 * 4);
        float* agg1 = (float*)ws; ws += align((size_t)N * 16 * 4);
        float* hs2  = (float*)ws; ws += align((size_t)N * 2 * 4);
        float* agg2 = (float*)ws; ws += align((size_t)N * 2 * 4);
        int gN = (N + TPB - 1) / TPB;
        int gE = (E + TPB - 1) / TPB;
        int gE4 = ((size_t)E * 4 + TPB - 1) / TPB;

        k_zero<<<gN, TPB, 0, stream>>>(deg, N);
        k_deg_fb<<<gE, TPB, 0, stream>>>(dst, deg, E);
        k_dis_fb<<<gN, TPB, 0, stream>>>(deg, dis, N);
        k_lin1_fb<<<gN, TPB, 0, stream>>>(x, W1, dis, hs1, agg1, N);
        k_scat1_fb<<<gE4, TPB, 0, stream>>>(src, dst, hs1, agg1, E * 4);
        k_lin2_fb<<<gN, TPB, 0, stream>>>(agg1, dis, b1, W2, hs2, agg2, N);
        k_scat2_fb<<<gE, TPB, 0, stream>>>(src, dst, hs2, agg2, E);
        k_out_fb<<<gN, TPB, 0, stream>>>(agg2, dis, b2, outp, N);
    }
}

// Round 6
// 470.806 us; speedup vs baseline: 4.7577x; 1.8652x over previous
//
#include <hip/hip_runtime.h>

#define TPB 256
#define BSH 7                 // nodes per bucket = 128
#define BNODES 128
#define EPW 8192              // edges per workgroup in passA

// ---------------- small utils ----------------

__global__ void k_zero(int* __restrict__ p, int n) {
    int i = blockIdx.x * blockDim.x + threadIdx.x;
    if (i < n) p[i] = 0;
}

// ---------------- bucket histogram (LDS-aggregated) ----------------

__global__ void k_hist(const int* __restrict__ dst, int* __restrict__ bcnt, int E, int NB) {
    extern __shared__ int cnt[];
    for (int i = threadIdx.x; i < NB; i += TPB) cnt[i] = 0;
    __syncthreads();
    int per = (E + gridDim.x - 1) / gridDim.x;
    int s = blockIdx.x * per;
    int e = min(E, s + per);
    for (int i = s + threadIdx.x; i < e; i += TPB)
        atomicAdd(&cnt[dst[i] >> BSH], 1);
    __syncthreads();
    for (int i = threadIdx.x; i < NB; i += TPB)
        if (cnt[i]) atomicAdd(&bcnt[i], cnt[i]);
}

// ---------------- exclusive scan of bucket counts (1 wg) ----------------

__global__ void k_scanb(const int* __restrict__ bcnt, int* __restrict__ bbase,
                        int* __restrict__ cursor, int NB) {
    __shared__ int sh[TPB];
    __shared__ int carry;
    if (threadIdx.x == 0) carry = 0;
    __syncthreads();
    for (int c0 = 0; c0 < NB; c0 += TPB) {
        int i = c0 + threadIdx.x;
        int v = (i < NB) ? bcnt[i] : 0;
        sh[threadIdx.x] = v;
        __syncthreads();
        for (int off = 1; off < TPB; off <<= 1) {
            int t = (threadIdx.x >= off) ? sh[threadIdx.x - off] : 0;
            __syncthreads();
            sh[threadIdx.x] += t;
            __syncthreads();
        }
        int total = sh[TPB - 1];
        int ex = carry + sh[threadIdx.x] - v;
        __syncthreads();
        if (threadIdx.x == 0) carry += total;
        __syncthreads();
        if (i < NB) { bbase[i] = ex; cursor[i] = ex; }
    }
    if (threadIdx.x == 0) bbase[NB] = carry;  // == E
}

// ---------------- pass A: partition edges into buckets, packed (src<<7|dstLocal) ----------------

__global__ void k_passA(const int* __restrict__ src, const int* __restrict__ dst,
                        int* __restrict__ cursor, unsigned* __restrict__ packed,
                        int E, int NB) {
    extern __shared__ int sh[];
    int* cnt = sh;          // [NB]
    int* wbase = sh + NB;   // [NB]
    for (int i = threadIdx.x; i < NB; i += TPB) cnt[i] = 0;
    __syncthreads();
    int base = blockIdx.x * EPW;
    int eend = min(E, base + EPW);
    for (int i = base + threadIdx.x; i < eend; i += TPB)
        atomicAdd(&cnt[dst[i] >> BSH], 1);
    __syncthreads();
    for (int b = threadIdx.x; b < NB; b += TPB) {
        int c = cnt[b];
        if (c) wbase[b] = atomicAdd(&cursor[b], c);
        cnt[b] = 0;
    }
    __syncthreads();
    for (int i = base + threadIdx.x; i < eend; i += TPB) {
        int d = dst[i];
        int b = d >> BSH;
        int r = atomicAdd(&cnt[b], 1);
        packed[wbase[b] + r] = ((unsigned)src[i] << BSH) | (unsigned)(d & (BNODES - 1));
    }
}

// ---------------- per-bucket: degree->dis; xs = x*dis (layer-1 aggregation input) ----------------

__global__ void k_prepx(const unsigned* __restrict__ packed, const int* __restrict__ bbase,
                        const float* __restrict__ x, float* __restrict__ dis,
                        float* __restrict__ xs, int N) {
    __shared__ int cnt[BNODES];
    int b = blockIdx.x;
    int node0 = b << BSH;
    if (threadIdx.x < BNODES) cnt[threadIdx.x] = 0;
    __syncthreads();
    int e0 = bbase[b], e1 = bbase[b + 1];
    for (int i = e0 + threadIdx.x; i < e1; i += TPB)
        atomicAdd(&cnt[packed[i] & (BNODES - 1)], 1);
    __syncthreads();
    int t = threadIdx.x;
    if (t < BNODES && node0 + t < N) {
        float di = rsqrtf((float)(cnt[t] + 1));  // +1 self-loop
        dis[node0 + t] = di;
        float4 xv = ((const float4*)x)[node0 + t];
        xv.x *= di; xv.y *= di; xv.z *= di; xv.w *= di;
        ((float4*)xs)[node0 + t] = xv;
    }
}

// ---------------- layer-1 edge pass: aggregate xs (16 B/edge, L2-resident table) ----------------

#define U1 4
#define A1S 5   // acc stride pad (gcd(5,32)=1 -> banks spread)

__global__ void k_agg1x(const unsigned* __restrict__ packed, const int* __restrict__ bbase,
                        const float* __restrict__ xs, float* __restrict__ partial1, int S1) {
    __shared__ float acc[BNODES * A1S];
    for (int i = threadIdx.x; i < BNODES * A1S; i += TPB) acc[i] = 0.0f;
    __syncthreads();
    int b = blockIdx.x / S1;
    int s = blockIdx.x - b * S1;
    int e0 = bbase[b], e1 = bbase[b + 1];
    int len = e1 - e0;
    int ce0 = e0 + (int)((long long)len * s / S1);
    int ce1 = e0 + (int)((long long)len * (s + 1) / S1);
    int e = ce0 + threadIdx.x;
    for (; e + (U1 - 1) * TPB < ce1; e += U1 * TPB) {
        unsigned pk[U1];
#pragma unroll
        for (int u = 0; u < U1; u++) pk[u] = packed[e + u * TPB];
        float4 m[U1];
#pragma unroll
        for (int u = 0; u < U1; u++)
            m[u] = ((const float4*)xs)[pk[u] >> BSH];
#pragma unroll
        for (int u = 0; u < U1; u++) {
            float* a = &acc[(pk[u] & (BNODES - 1)) * A1S];
            atomicAdd(a + 0, m[u].x);
            atomicAdd(a + 1, m[u].y);
            atomicAdd(a + 2, m[u].z);
            atomicAdd(a + 3, m[u].w);
        }
    }
    for (; e < ce1; e += TPB) {
        unsigned pk = packed[e];
        float4 m = ((const float4*)xs)[pk >> BSH];
        float* a = &acc[(pk & (BNODES - 1)) * A1S];
        atomicAdd(a + 0, m.x);
        atomicAdd(a + 1, m.y);
        atomicAdd(a + 2, m.z);
        atomicAdd(a + 3, m.w);
    }
    __syncthreads();
    float* p = partial1 + (size_t)blockIdx.x * (BNODES * 4);
    for (int i = threadIdx.x; i < BNODES * 4; i += TPB)
        p[i] = acc[(i >> 2) * A1S + (i & 3)];
}

// ---------------- layer-1 combine: (+self) -> @W1 + b1 -> relu -> @W2 -> *dis ----------------

__global__ void k_comb1(const float* __restrict__ partial1, const float* __restrict__ xs,
                        const float* __restrict__ dis, const float* __restrict__ W1,
                        const float* __restrict__ b1, const float* __restrict__ W2,
                        float* __restrict__ hs2, int S1, int N) {
    __shared__ float w1[64];
    __shared__ float w2[32];
    __shared__ float bb[16];
    if (threadIdx.x < 64) w1[threadIdx.x] = W1[threadIdx.x];
    if (threadIdx.x < 32) w2[threadIdx.x] = W2[threadIdx.x];
    if (threadIdx.x < 16) bb[threadIdx.x] = b1[threadIdx.x];
    __syncthreads();
    int b = blockIdx.x;
    int node0 = b << BSH;
    int t = threadIdx.x;
    if (t >= BNODES || node0 + t >= N) return;
    float4 sum = ((const float4*)xs)[node0 + t];  // self-loop term
    for (int s = 0; s < S1; s++) {
        float4 v = ((const float4*)partial1)[(size_t)(b * S1 + s) * BNODES + t];
        sum.x += v.x; sum.y += v.y; sum.z += v.z; sum.w += v.w;
    }
    float di = dis[node0 + t];
    float v0 = sum.x * di, v1 = sum.y * di, v2 = sum.z * di, v3 = sum.w * di;
    float s0 = 0.f, s1 = 0.f;
#pragma unroll
    for (int j = 0; j < 16; j++) {
        float h = v0 * w1[j] + v1 * w1[16 + j] + v2 * w1[32 + j] + v3 * w1[48 + j] + bb[j];
        h = fmaxf(h, 0.0f);
        s0 += h * w2[2 * j];
        s1 += h * w2[2 * j + 1];
    }
    ((float2*)hs2)[node0 + t] = make_float2(s0 * di, s1 * di);
}

// ---------------- layer-2 edge pass: aggregate hs2 (8 B/edge, L2-resident table) ----------------

#define U2 4
#define A2S 3   // acc stride pad (gcd(3,32)=1)

__global__ void k_agg2x(const unsigned* __restrict__ packed, const int* __restrict__ bbase,
                        const float* __restrict__ hs2, float* __restrict__ partial2, int S2) {
    __shared__ float acc[BNODES * A2S];
    for (int i = threadIdx.x; i < BNODES * A2S; i += TPB) acc[i] = 0.0f;
    __syncthreads();
    int b = blockIdx.x / S2;
    int s = blockIdx.x - b * S2;
    int e0 = bbase[b], e1 = bbase[b + 1];
    int len = e1 - e0;
    int ce0 = e0 + (int)((long long)len * s / S2);
    int ce1 = e0 + (int)((long long)len * (s + 1) / S2);
    int e = ce0 + threadIdx.x;
    for (; e + (U2 - 1) * TPB < ce1; e += U2 * TPB) {
        unsigned pk[U2];
#pragma unroll
        for (int u = 0; u < U2; u++) pk[u] = packed[e + u * TPB];
        float2 m[U2];
#pragma unroll
        for (int u = 0; u < U2; u++)
            m[u] = ((const float2*)hs2)[pk[u] >> BSH];
#pragma unroll
        for (int u = 0; u < U2; u++) {
            float* a = &acc[(pk[u] & (BNODES - 1)) * A2S];
            atomicAdd(a + 0, m[u].x);
            atomicAdd(a + 1, m[u].y);
        }
    }
    for (; e < ce1; e += TPB) {
        unsigned pk = packed[e];
        float2 m = ((const float2*)hs2)[pk >> BSH];
        float* a = &acc[(pk & (BNODES - 1)) * A2S];
        atomicAdd(a + 0, m.x);
        atomicAdd(a + 1, m.y);
    }
    __syncthreads();
    float* p = partial2 + (size_t)blockIdx.x * (BNODES * 2);
    for (int i = threadIdx.x; i < BNODES * 2; i += TPB)
        p[i] = acc[(i >> 1) * A2S + (i & 1)];
}

// ---------------- layer-2 combine + final bias -> out ----------------

__global__ void k_comb2(const float* __restrict__ partial2, const float* __restrict__ hs2,
                        const float* __restrict__ dis, const float* __restrict__ b2,
                        float* __restrict__ out, int S2, int N) {
    int b = blockIdx.x;
    int node0 = b << BSH;
    int v = threadIdx.x >> 1;
    int f = threadIdx.x & 1;
    if (v >= BNODES || node0 + v >= N) return;
    float sum = hs2[(size_t)(node0 + v) * 2 + f];  // self-loop
    for (int s = 0; s < S2; s++)
        sum += partial2[((size_t)b * S2 + s) * (BNODES * 2) + v * 2 + f];
    out[(size_t)(node0 + v) * 2 + f] = sum * dis[node0 + v] + b2[f];
}

// ---------------- fallback (R1 atomic pipeline) ----------------

__global__ void k_deg_fb(const int* __restrict__ dst, int* __restrict__ deg, int E) {
    int i = blockIdx.x * blockDim.x + threadIdx.x;
    if (i < E) atomicAdd(&deg[dst[i]], 1);
}
__global__ void k_dis_fb(const int* __restrict__ deg, float* __restrict__ dis, int N) {
    int v = blockIdx.x * blockDim.x + threadIdx.x;
    if (v < N) dis[v] = rsqrtf((float)(deg[v] + 1));
}
__global__ void k_lin1_fb(const float* __restrict__ x, const float* __restrict__ W1,
                          const float* __restrict__ dis, float* __restrict__ hs1,
                          float* __restrict__ agg1, int N) {
    __shared__ float w[64];
    if (threadIdx.x < 64) w[threadIdx.x] = W1[threadIdx.x];
    __syncthreads();
    int v = blockIdx.x * blockDim.x + threadIdx.x;
    if (v >= N) return;
    float4 xv = ((const float4*)x)[v];
    float d = dis[v];
#pragma unroll
    for (int j = 0; j < 16; j++) {
        float h = (xv.x * w[j] + xv.y * w[16 + j] + xv.z * w[32 + j] + xv.w * w[48 + j]) * d;
        hs1[v * 16 + j] = h;
        agg1[v * 16 + j] = h;
    }
}
__global__ void k_scat1_fb(const int* __restrict__ src, const int* __restrict__ dst,
                           const float* __restrict__ hs1, float* __restrict__ agg1, int E4) {
    int t = blockIdx.x * blockDim.x + threadIdx.x;
    if (t >= E4) return;
    int e = t >> 2, q = t & 3;
    int s = src[e], d = dst[e];
    float4 m = ((const float4*)hs1)[s * 4 + q];
    float* a = agg1 + (size_t)d * 16 + q * 4;
    atomicAdd(a + 0, m.x); atomicAdd(a + 1, m.y);
    atomicAdd(a + 2, m.z); atomicAdd(a + 3, m.w);
}
__global__ void k_lin2_fb(const float* __restrict__ agg1, const float* __restrict__ dis,
                          const float* __restrict__ b1, const float* __restrict__ W2,
                          float* __restrict__ hs2, float* __restrict__ agg2, int N) {
    __shared__ float w[32];
    __shared__ float bb[16];
    if (threadIdx.x < 32) w[threadIdx.x] = W2[threadIdx.x];
    if (threadIdx.x < 16) bb[threadIdx.x] = b1[threadIdx.x];
    __syncthreads();
    int v = blockIdx.x * blockDim.x + threadIdx.x;
    if (v >= N) return;
    float d = dis[v];
    float a0 = 0.f, a1 = 0.f;
#pragma unroll
    for (int k = 0; k < 16; k++) {
        float r = fmaxf(agg1[v * 16 + k] * d + bb[k], 0.0f);
        a0 += r * w[k * 2 + 0];
        a1 += r * w[k * 2 + 1];
    }
    float2 hv = make_float2(a0 * d, a1 * d);
    ((float2*)hs2)[v] = hv;
    ((float2*)agg2)[v] = hv;
}
__global__ void k_scat2_fb(const int* __restrict__ src, const int* __restrict__ dst,
                           const float* __restrict__ hs2, float* __restrict__ agg2, int E) {
    int e = blockIdx.x * blockDim.x + threadIdx.x;
    if (e >= E) return;
    int s = src[e], d = dst[e];
    float2 m = ((const float2*)hs2)[s];
    atomicAdd(&agg2[d * 2 + 0], m.x);
    atomicAdd(&agg2[d * 2 + 1], m.y);
}
__global__ void k_out_fb(const float* __restrict__ agg2, const float* __restrict__ dis,
                         const float* __restrict__ b2, float* __restrict__ out, int N) {
    int v = blockIdx.x * blockDim.x + threadIdx.x;
    if (v >= N) return;
    float d = dis[v];
    out[v * 2 + 0] = agg2[v * 2 + 0] * d + b2[0];
    out[v * 2 + 1] = agg2[v * 2 + 1] * d + b2[1];
}

// ---------------- launch ----------------

extern "C" void kernel_launch(void* const* d_in, const int* in_sizes, int n_in,
                              void* d_out, int out_size, void* d_ws, size_t ws_size,
                              hipStream_t stream) {
    const float* x  = (const float*)d_in[0];
    const int*   ei = (const int*)d_in[1];
    const float* W1 = (const float*)d_in[2];
    const float* b1 = (const float*)d_in[3];
    const float* W2 = (const float*)d_in[4];
    const float* b2 = (const float*)d_in[5];

    const int N = in_sizes[0] / 4;   // 100000
    const int E = in_sizes[1] / 2;   // 6400000
    const int* src = ei;
    const int* dst = ei + E;
    float* outp = (float*)d_out;

    auto align = [](size_t v) { return (v + 255) & ~(size_t)255; };
    const int NB = (N + BNODES - 1) >> BSH;

    size_t base_need = align((size_t)E * 4)          /* packed */
                     + align((size_t)N * 4)          /* dis */
                     + align((size_t)N * 16)         /* xs (N float4) */
                     + align((size_t)N * 8)          /* hs2 */
                     + align((size_t)NB * 4) * 2     /* bcnt, cursor */
                     + align((size_t)(NB + 1) * 4);  /* bbase */
    auto part_need = [&](int S1, int S2) {
        return align((size_t)NB * S1 * BNODES * 4 * 4)
             + align((size_t)NB * S2 * BNODES * 2 * 4);
    };

    int S1 = 8, S2 = 8;
    if (base_need + part_need(S1, S2) > ws_size) { S1 = 8; S2 = 4; }
    if (base_need + part_need(S1, S2) > ws_size) { S1 = 4; S2 = 4; }
    if (base_need + part_need(S1, S2) > ws_size) { S1 = 2; S2 = 2; }
    if (base_need + part_need(S1, S2) > ws_size) { S1 = 1; S2 = 1; }

    if (base_need + part_need(S1, S2) <= ws_size && (size_t)N <= (1u << 25) && NB <= 4096) {
        char* ws = (char*)d_ws;
        unsigned* packed = (unsigned*)ws; ws += align((size_t)E * 4);
        float* dis  = (float*)ws; ws += align((size_t)N * 4);
        float* xs   = (float*)ws; ws += align((size_t)N * 16);
        float* hs2  = (float*)ws; ws += align((size_t)N * 8);
        int* bcnt   = (int*)ws;   ws += align((size_t)NB * 4);
        int* cursor = (int*)ws;   ws += align((size_t)NB * 4);
        int* bbase  = (int*)ws;   ws += align((size_t)(NB + 1) * 4);
        float* partial1 = (float*)ws; ws += align((size_t)NB * S1 * BNODES * 4 * 4);
        float* partial2 = (float*)ws; ws += align((size_t)NB * S2 * BNODES * 2 * 4);

        int gA = (E + EPW - 1) / EPW;

        k_zero<<<(NB + TPB - 1) / TPB, TPB, 0, stream>>>(bcnt, NB);
        k_hist<<<512, TPB, (size_t)NB * 4, stream>>>(dst, bcnt, E, NB);
        k_scanb<<<1, TPB, 0, stream>>>(bcnt, bbase, cursor, NB);
        k_passA<<<gA, TPB, (size_t)NB * 8, stream>>>(src, dst, cursor, packed, E, NB);
        k_prepx<<<NB, TPB, 0, stream>>>(packed, bbase, x, dis, xs, N);
        k_agg1x<<<NB * S1, TPB, 0, stream>>>(packed, bbase, xs, partial1, S1);
        k_comb1<<<NB, 128, 0, stream>>>(partial1, xs, dis, W1, b1, W2, hs2, S1, N);
        k_agg2x<<<NB * S2, TPB, 0, stream>>>(packed, bbase, hs2, partial2, S2);
        k_comb2<<<NB, TPB, 0, stream>>>(partial2, hs2, dis, b2, outp, S2, N);
    } else {
        // fallback: R1 atomic-scatter pipeline
        char* ws = (char*)d_ws;
        int*   deg  = (int*)ws;   ws += align((size_t)N * 4);
        float* dis  = (float*)ws; ws += align((size_t)N * 4);
        float* hs1  = (float*)ws; ws += align((size_t)N * 16 * 4);
        float* agg1 = (float*)ws; ws += align((size_t)N * 16 * 4);
        float* hs2  = (float*)ws; ws += align((size_t)N * 2 * 4);
        float* agg2 = (float*)ws; ws += align((size_t)N * 2 * 4);
        int gN = (N + TPB - 1) / TPB;
        int gE = (E + TPB - 1) / TPB;
        int gE4 = ((size_t)E * 4 + TPB - 1) / TPB;

        k_zero<<<gN, TPB, 0, stream>>>(deg, N);
        k_deg_fb<<<gE, TPB, 0, stream>>>(dst, deg, E);
        k_dis_fb<<<gN, TPB, 0, stream>>>(deg, dis, N);
        k_lin1_fb<<<gN, TPB, 0, stream>>>(x, W1, dis, hs1, agg1, N);
        k_scat1_fb<<<gE4, TPB, 0, stream>>>(src, dst, hs1, agg1, E * 4);
        k_lin2_fb<<<gN, TPB, 0, stream>>>(agg1, dis, b1, W2, hs2, agg2, N);
        k_scat2_fb<<<gE, TPB, 0, stream>>>(src, dst, hs2, agg2, E);
        k_out_fb<<<gN, TPB, 0, stream>>>(agg2, dis, b2, outp, N);
    }
}